// Round 15
// baseline (188.158 us; speedup 1.0000x reference)
//
#include <hip/hip_runtime.h>
#include <math.h>

#define B_ 2
#define L_ 2048
#define D_ 512
#define H_ 8
#define DH 64
#define NS 2048   // U_part (sampled keys)
#define NU 40     // u (selected queries)
#define BHD (L_*D_)        // per-batch stride of qp/kp/vp
#define QHS (L_*DH)        // per-head stride inside qh view
#define WSPM 786432        // ushorts per mat in the W-split buffer

typedef __attribute__((ext_vector_type(8))) short bf16x8;
typedef __attribute__((ext_vector_type(4))) float f32x4;

__device__ inline float4 ld4(const float* p) { return *reinterpret_cast<const float4*>(p); }

// truncation split: x = h + m + r, all bf16-representable (exact truncations).
// 6-product MFMA (hh,hm,mh,mm,hl,lh) == fp32-class dot.
__device__ inline unsigned short hi16(float x) { return (unsigned short)(__float_as_uint(x) >> 16); }
__device__ inline float trunchf(float x) { return __uint_as_float(__float_as_uint(x) & 0xFFFF0000u); }
__device__ inline void tsplit(float x, unsigned short& hs, unsigned short& ms, unsigned short& ls) {
  float h = trunchf(x); hs = hi16(x);
  float r = x - h;                 // exact
  float m = trunchf(r); ms = hi16(r);
  float r2 = r - m;                // exact
  ls = hi16(r2);
}

// ---------------------------------------------------------------- W pre-split into fragment-direct layout
__global__ __launch_bounds__(256) void wsplit(const float* __restrict__ Wq,
                                              const float* __restrict__ Wk,
                                              const float* __restrict__ Wv,
                                              unsigned short* __restrict__ dst,
                                              int matArg) {
  const int mat = (matArg >= 0) ? matArg : (int)blockIdx.y;
  const float* W = (mat == 0) ? Wq : (mat == 1) ? Wk : Wv;
  unsigned short* d = dst + ((matArg >= 0) ? 0 : (size_t)mat * WSPM);
  const int t = threadIdx.x;
  const int nt = blockIdx.x >> 3, g16 = blockIdx.x & 7;
  const int kc = t >> 4, lr = t & 15;
  const int n = nt*128 + g16*16 + lr;
  const float* src = W + (size_t)n*512 + kc*32;
  float xs[32];
#pragma unroll
  for (int i = 0; i < 8; ++i) {
    float4 v4 = ld4(src + 4*i);
    xs[4*i] = v4.x; xs[4*i+1] = v4.y; xs[4*i+2] = v4.z; xs[4*i+3] = v4.w;
  }
  unsigned short Hs[32], Ms[32], Ls[32];
#pragma unroll
  for (int e = 0; e < 32; ++e) tsplit(xs[e], Hs[e], Ms[e], Ls[e]);
#pragma unroll
  for (int p = 0; p < 3; ++p) {
    const unsigned short* sp = (p == 0) ? Hs : (p == 1) ? Ms : Ls;
    unsigned short* base = d + ((size_t)((p*4 + nt)*8 + g16)*16 + kc)*512;
#pragma unroll
    for (int lg = 0; lg < 4; ++lg) {
      union { bf16x8 v; unsigned short u[8]; } P;
#pragma unroll
      for (int e = 0; e < 8; ++e) P.u[e] = sp[lg*8 + e];
      *reinterpret_cast<bf16x8*>(base + (lr + 16*lg)*8) = P.v;
    }
  }
}

// ---------------------------------------------------------------- projection GEMM, small-tile split-bf16 MFMA
// Block 64x128 (4 waves, each 64x32: mi=4, ni=2). Grid 768 = 3 blocks/CU.
__global__ __launch_bounds__(256, 3) void proj_s(
    const float* __restrict__ qa, const float* __restrict__ ka, const float* __restrict__ va,
    const unsigned short* __restrict__ wsp,
    const float* __restrict__ bq, const float* __restrict__ bk, const float* __restrict__ bv,
    float* __restrict__ qp, float* __restrict__ kp, float* __restrict__ vp,
    int matArg)
{
  __shared__ __align__(16) unsigned short a3[2][3][64][36];
  const int t = threadIdx.x;
  const int mat = (matArg >= 0) ? matArg : (int)blockIdx.z;
  const float* A    = (mat == 0) ? qa : (mat == 1) ? ka : va;
  const float* bias = (mat == 0) ? bq : (mat == 1) ? bk : bv;
  float* C          = (mat == 0) ? qp : (mat == 1) ? kp : vp;
  const unsigned short* wspm = wsp + ((matArg >= 0) ? 0 : (size_t)mat * WSPM);
  const int m0 = blockIdx.x * 64, NT = blockIdx.y;
  const int wn = t >> 6, l = t & 63;
  const int lr = l & 15, lg = l >> 4;
  const int srow = t >> 2, scf = (t & 3) * 8;
  const float* aRow = A + (size_t)(m0 + srow) * 512 + scf;

  f32x4 acc[4][2];
#pragma unroll
  for (int i = 0; i < 4; ++i)
#pragma unroll
    for (int j = 0; j < 2; ++j) acc[i][j] = (f32x4){0.f, 0.f, 0.f, 0.f};

#define LOADW(dst, kcv)                                                        \
  _Pragma("unroll")                                                            \
  for (int p = 0; p < 3; ++p)                                                  \
    _Pragma("unroll")                                                          \
    for (int ni = 0; ni < 2; ++ni)                                             \
      dst[p][ni] = *reinterpret_cast<const bf16x8*>(                           \
          wspm + ((size_t)((p*4 + NT)*8 + wn*2 + ni)*16 + (kcv))*512 + l*8);

#define SPLITSTORE(r0, r1, buf)                                                \
  {                                                                            \
    float xs[8] = {r0.x, r0.y, r0.z, r0.w, r1.x, r1.y, r1.z, r1.w};            \
    union { bf16x8 v; unsigned short u[8]; } H, M, L;                          \
    _Pragma("unroll")                                                          \
    for (int e = 0; e < 8; ++e) tsplit(xs[e], H.u[e], M.u[e], L.u[e]);         \
    *reinterpret_cast<bf16x8*>(&a3[buf][0][srow][scf]) = H.v;                  \
    *reinterpret_cast<bf16x8*>(&a3[buf][1][srow][scf]) = M.v;                  \
    *reinterpret_cast<bf16x8*>(&a3[buf][2][srow][scf]) = L.v;                  \
  }

#define MFMA6(buf, bw)                                                         \
  __builtin_amdgcn_s_setprio(1);                                               \
  _Pragma("unroll")                                                            \
  for (int mi = 0; mi < 4; ++mi) {                                             \
    bf16x8 a0 = *reinterpret_cast<const bf16x8*>(&a3[buf][0][mi*16 + lr][lg*8]); \
    bf16x8 a1 = *reinterpret_cast<const bf16x8*>(&a3[buf][1][mi*16 + lr][lg*8]); \
    bf16x8 a2 = *reinterpret_cast<const bf16x8*>(&a3[buf][2][mi*16 + lr][lg*8]); \
    _Pragma("unroll")                                                          \
    for (int ni = 0; ni < 2; ++ni) {                                           \
      acc[mi][ni] = __builtin_amdgcn_mfma_f32_16x16x32_bf16(a0, bw[0][ni], acc[mi][ni], 0, 0, 0); \
      acc[mi][ni] = __builtin_amdgcn_mfma_f32_16x16x32_bf16(a0, bw[1][ni], acc[mi][ni], 0, 0, 0); \
      acc[mi][ni] = __builtin_amdgcn_mfma_f32_16x16x32_bf16(a1, bw[0][ni], acc[mi][ni], 0, 0, 0); \
      acc[mi][ni] = __builtin_amdgcn_mfma_f32_16x16x32_bf16(a1, bw[1][ni], acc[mi][ni], 0, 0, 0); \
      acc[mi][ni] = __builtin_amdgcn_mfma_f32_16x16x32_bf16(a0, bw[2][ni], acc[mi][ni], 0, 0, 0); \
      acc[mi][ni] = __builtin_amdgcn_mfma_f32_16x16x32_bf16(a2, bw[0][ni], acc[mi][ni], 0, 0, 0); \
    }                                                                          \
  }                                                                            \
  __builtin_amdgcn_s_setprio(0);

  float4 arA0 = ld4(aRow), arA1 = ld4(aRow + 4);
  bf16x8 bwA[3][2], bwB[3][2];
  LOADW(bwA, 0);
  float4 arB0, arB1;

  for (int kc = 0; kc < 16; kc += 2) {
    SPLITSTORE(arA0, arA1, 0);
    __syncthreads();
    if (kc < 15) {
      const float* src = aRow + (kc+1)*32;
      arB0 = ld4(src); arB1 = ld4(src + 4);
      LOADW(bwB, kc+1);
    }
    MFMA6(0, bwA);
    SPLITSTORE(arB0, arB1, 1);
    __syncthreads();
    if (kc + 2 < 16) {
      const float* src = aRow + (kc+2)*32;
      arA0 = ld4(src); arA1 = ld4(src + 4);
      LOADW(bwA, kc+2);
    }
    MFMA6(1, bwB);
  }
#undef LOADW
#undef SPLITSTORE
#undef MFMA6

#pragma unroll
  for (int mi = 0; mi < 4; ++mi)
#pragma unroll
    for (int ni = 0; ni < 2; ++ni) {
      const int gn = NT*128 + wn*32 + ni*16 + lr;
      const float bv_ = bias[gn];
#pragma unroll
      for (int r = 0; r < 4; ++r) {
        const int gm = m0 + mi*16 + lg*4 + r;
        C[(size_t)gm * 512 + gn] = acc[mi][ni][r] + bv_;
      }
    }
}

// ---------------------------------------------------------------- ksum partials, 8-way parallel over samples
// kpart[(bh*8+pr)*64 + j] = sum over samples pr*256..+256 of kp[b, idx[s], h*64+j]
__global__ __launch_bounds__(1024) void ksum_part(const float* __restrict__ kp,
                                                  const int* __restrict__ idx,
                                                  float* __restrict__ kpart) {
  __shared__ float part[16][64];
  const int bh = blockIdx.x, pr = blockIdx.y;
  const int b = bh >> 3, h = bh & 7;
  const int t = threadIdx.x;
  const int sg = t >> 6, j = t & 63;
  const float* kbase = kp + (size_t)b*BHD + h*DH;
  const int s0 = pr*256 + sg*16;
  float a = 0.f;
  for (int s = s0; s < s0 + 16; ++s)
    a += kbase[(size_t)idx[s]*512 + j];
  part[sg][j] = a;
  __syncthreads();
  if (t < 64) {
    float s = 0.f;
#pragma unroll
    for (int i = 0; i < 16; ++i) s += part[i][t];
    kpart[(bh*8 + pr)*64 + t] = s;
  }
}

// ---------------------------------------------------------------- dedupe sampled indices (max over multiset == max over unique set)
__global__ __launch_bounds__(256) void dedupe(const int* __restrict__ idx,
                                              int* __restrict__ ulist,
                                              int* __restrict__ ucnt) {
  __shared__ unsigned bm[64];
  __shared__ int base[64];
  __shared__ int total;
  const int t = threadIdx.x;
  if (t < 64) bm[t] = 0;
  __syncthreads();
#pragma unroll
  for (int c = 0; c < 8; ++c) {
    const int v = idx[c*256 + t];
    atomicOr(&bm[v >> 5], 1u << (v & 31));
  }
  __syncthreads();
  if (t < 64) {
    const int cnt = __popc(bm[t]);
    int inc = cnt;
#pragma unroll
    for (int off = 1; off < 64; off <<= 1) {
      const int nb = __shfl_up(inc, off);
      if (t >= off) inc += nb;
    }
    base[t] = inc - cnt;
    if (t == 63) total = inc;
  }
  __syncthreads();
  if (t < 64) {
    unsigned w = bm[t];
    int pos = base[t];
    while (w) {
      const int b = __ffs(w) - 1;
      w &= w - 1;
      ulist[pos++] = t*32 + b;
    }
  }
  __syncthreads();
  const int U = total;
  const int nt = (U + 127) >> 7;
  const int padded = nt << 7;
  const int first = ulist[0];
  for (int p = U + t; p < padded; p += 256) ulist[p] = first;
  if (t == 0) ucnt[0] = nt;
}

// ---------------------------------------------------------------- Mp[ks][bh][q] = max over this ks-slice of unique keys
__global__ __launch_bounds__(256, 2) void m_kernel(const float* __restrict__ qp,
                                                   const float* __restrict__ kp,
                                                   const int* __restrict__ ulist,
                                                   const int* __restrict__ ucnt,
                                                   float* __restrict__ Mp) {
  __shared__ __align__(16) unsigned short k3[3][128][72];
  const int t = threadIdx.x;
  const int bid = blockIdx.x;
  const int bh = bid >> 5, qt = (bid >> 2) & 7, ks = bid & 3;
  const int b = bh >> 3, h = bh & 7;
  const int w = t >> 6, l = t & 63;
  const int lr = l & 15;
  const int lg = l >> 4;

  bf16x8 qf[4][2][3];
  {
    const float* qbase = qp + (size_t)b*BHD + (size_t)h*QHS + (size_t)(qt*256 + w*64 + lr) * 64 + lg*8;
#pragma unroll
    for (int mi = 0; mi < 4; ++mi)
#pragma unroll
      for (int c = 0; c < 2; ++c) {
        const float* src = qbase + mi*16*64 + c*32;
        float4 x0 = ld4(src), x1 = ld4(src + 4);
        float xs[8] = {x0.x, x0.y, x0.z, x0.w, x1.x, x1.y, x1.z, x1.w};
        union { bf16x8 v; unsigned short u[8]; } H, M, L;
#pragma unroll
        for (int e = 0; e < 8; ++e) tsplit(xs[e], H.u[e], M.u[e], L.u[e]);
        qf[mi][c][0] = H.v; qf[mi][c][1] = M.v; qf[mi][c][2] = L.v;
      }
  }

  const float* kbase = kp + (size_t)b*BHD + h*DH;
  const int ntiles = ucnt[0];
  const int srow = t >> 1, sh = (t & 1) * 32;

  float4 vst[8];
  if (ks < ntiles) {
    const int kr = ulist[ks*128 + srow];
    const float* src = kbase + (size_t)kr * 512 + sh;
#pragma unroll
    for (int i = 0; i < 8; ++i) vst[i] = ld4(src + 4*i);
  }

  float mx[4][4];
#pragma unroll
  for (int mi = 0; mi < 4; ++mi)
#pragma unroll
    for (int r = 0; r < 4; ++r) mx[mi][r] = -INFINITY;

  for (int ti = ks; ti < ntiles; ti += 4) {
    __syncthreads();
    {
#pragma unroll
      for (int e2 = 0; e2 < 4; ++e2) {
        union { bf16x8 v; unsigned short u[8]; } H, M, L;
        float xs[8] = {vst[2*e2].x, vst[2*e2].y, vst[2*e2].z, vst[2*e2].w,
                       vst[2*e2+1].x, vst[2*e2+1].y, vst[2*e2+1].z, vst[2*e2+1].w};
#pragma unroll
        for (int e = 0; e < 8; ++e) tsplit(xs[e], H.u[e], M.u[e], L.u[e]);
        *reinterpret_cast<bf16x8*>(&k3[0][srow][sh + 8*e2]) = H.v;
        *reinterpret_cast<bf16x8*>(&k3[1][srow][sh + 8*e2]) = M.v;
        *reinterpret_cast<bf16x8*>(&k3[2][srow][sh + 8*e2]) = L.v;
      }
    }
    if (ti + 4 < ntiles) {
      const int kr = ulist[(ti+4)*128 + srow];
      const float* src = kbase + (size_t)kr * 512 + sh;
#pragma unroll
      for (int i = 0; i < 8; ++i) vst[i] = ld4(src + 4*i);
    }
    __syncthreads();

    for (int n2 = 0; n2 < 4; ++n2) {
      bf16x8 bf[2][3][2];
#pragma unroll
      for (int ns = 0; ns < 2; ++ns)
#pragma unroll
        for (int p = 0; p < 3; ++p)
#pragma unroll
          for (int c = 0; c < 2; ++c)
            bf[ns][p][c] = *reinterpret_cast<const bf16x8*>(&k3[p][n2*32 + ns*16 + lr][c*32 + lg*8]);
      __builtin_amdgcn_s_setprio(1);
#pragma unroll
      for (int mi = 0; mi < 4; ++mi)
#pragma unroll
        for (int ns = 0; ns < 2; ++ns) {
          f32x4 acc = {0.f, 0.f, 0.f, 0.f};
#pragma unroll
          for (int c = 0; c < 2; ++c) acc = __builtin_amdgcn_mfma_f32_16x16x32_bf16(qf[mi][c][0], bf[ns][0][c], acc, 0, 0, 0); // hh
#pragma unroll
          for (int c = 0; c < 2; ++c) acc = __builtin_amdgcn_mfma_f32_16x16x32_bf16(qf[mi][c][0], bf[ns][1][c], acc, 0, 0, 0); // hm
#pragma unroll
          for (int c = 0; c < 2; ++c) acc = __builtin_amdgcn_mfma_f32_16x16x32_bf16(qf[mi][c][1], bf[ns][0][c], acc, 0, 0, 0); // mh
#pragma unroll
          for (int c = 0; c < 2; ++c) acc = __builtin_amdgcn_mfma_f32_16x16x32_bf16(qf[mi][c][1], bf[ns][1][c], acc, 0, 0, 0); // mm
#pragma unroll
          for (int c = 0; c < 2; ++c) acc = __builtin_amdgcn_mfma_f32_16x16x32_bf16(qf[mi][c][0], bf[ns][2][c], acc, 0, 0, 0); // hl
#pragma unroll
          for (int c = 0; c < 2; ++c) acc = __builtin_amdgcn_mfma_f32_16x16x32_bf16(qf[mi][c][2], bf[ns][0][c], acc, 0, 0, 0); // lh
#pragma unroll
          for (int r = 0; r < 4; ++r) mx[mi][r] = fmaxf(mx[mi][r], acc[r]);
        }
      __builtin_amdgcn_s_setprio(0);
    }
  }

#pragma unroll
  for (int mi = 0; mi < 4; ++mi)
#pragma unroll
    for (int r = 0; r < 4; ++r) {
      float v = mx[mi][r];
      v = fmaxf(v, __shfl_xor(v, 1));
      v = fmaxf(v, __shfl_xor(v, 2));
      v = fmaxf(v, __shfl_xor(v, 4));
      v = fmaxf(v, __shfl_xor(v, 8));
      if (lr == 0)
        Mp[ks*32768 + bh*2048 + qt*256 + w*64 + mi*16 + lg*4 + r] = v;
    }
}

// ---------------------------------------------------------------- fused M-finalize + top-40 via radix-select
__global__ __launch_bounds__(256) void topk_kernel(const float* __restrict__ qp,
                                                   const float* __restrict__ kpart,
                                                   const float* __restrict__ Mp,
                                                   int* __restrict__ Mtop) {
  __shared__ float ks_s[64];
  __shared__ unsigned hist[256];
  __shared__ int wsum[4];
  __shared__ unsigned bitmap[64];
  __shared__ unsigned long long comb[NU];
  __shared__ int s_sel, s_rem, s_cnt;
  const int bh = blockIdx.x;
  const int b = bh >> 3, h = bh & 7;
  const int t = threadIdx.x;
  if (t < 64) {
    float s = 0.f;
#pragma unroll
    for (int p = 0; p < 8; ++p) s += kpart[(bh*8 + p)*64 + t];
    ks_s[t] = s;
  }
  __syncthreads();

  unsigned mykey[8];
#pragma unroll
  for (int c = 0; c < 8; ++c) {
    const int qi = c * 256 + t;
    const float* qrow = qp + (size_t)b*BHD + (size_t)h*QHS + (size_t)qi * 64;
    float dot = 0.f;
#pragma unroll
    for (int cc = 0; cc < 16; ++cc) {
      float4 q4 = ld4(qrow + 4 * cc);
      dot += q4.x * ks_s[4*cc + 0];
      dot += q4.y * ks_s[4*cc + 1];
      dot += q4.z * ks_s[4*cc + 2];
      dot += q4.w * ks_s[4*cc + 3];
    }
    const float mx2 = fmaxf(fmaxf(Mp[bh*2048 + qi], Mp[32768 + bh*2048 + qi]),
                            fmaxf(Mp[65536 + bh*2048 + qi], Mp[98304 + bh*2048 + qi]));
    const float m = mx2 - dot * (1.0f/2048.0f);
    const unsigned u = __float_as_uint(m);
    mykey[c] = (u >> 31) ? ~u : (u | 0x80000000u);
  }

  unsigned prefMask = 0u, prefVal = 0u;
  int rem = NU;
  for (int shift = 24; shift >= 0; shift -= 8) {
    hist[t] = 0;
    __syncthreads();
#pragma unroll
    for (int c = 0; c < 8; ++c) {
      const unsigned key = mykey[c];
      if ((key & prefMask) == prefVal)
        atomicAdd(&hist[(key >> shift) & 255], 1u);
    }
    __syncthreads();
    const int binc = (int)hist[t];
    int inc = binc;
#pragma unroll
    for (int off = 1; off < 64; off <<= 1) {
      const int nb = __shfl_up(inc, off);
      if ((t & 63) >= off) inc += nb;
    }
    if ((t & 63) == 63) wsum[t >> 6] = inc;
    __syncthreads();
    int wadd = 0;
    for (int w2 = 0; w2 < (t >> 6); ++w2) wadd += wsum[w2];
    const int incl = inc + wadd;
    const int excl = incl - binc;
    if (excl < rem && rem <= incl) { s_sel = t; s_rem = rem - excl; }
    __syncthreads();
    prefVal |= ((unsigned)s_sel) << shift;
    prefMask |= 0xFFu << shift;
    rem = s_rem;
    __syncthreads();
  }
  const unsigned T = prefVal;

  if (t < 64) bitmap[t] = 0;
  if (t == 0) s_cnt = 0;
  __syncthreads();
#pragma unroll
  for (int c = 0; c < 8; ++c) {
    const unsigned key = mykey[c];
    const int qi = c * 256 + t;
    if (key < T) {
      const int pos = atomicAdd(&s_cnt, 1);
      comb[pos] = ((unsigned long long)key << 11) | (unsigned)qi;
    } else if (key == T) {
      atomicOr(&bitmap[qi >> 5], 1u << (qi & 31));
    }
  }
  __syncthreads();
  if (t == 0) {
    int need = rem, cpos = s_cnt;
    for (int wd = 0; wd < 64 && need > 0; ++wd) {
      unsigned bits = bitmap[wd];
      while (bits && need > 0) {
        const int bit = __ffs(bits) - 1;
        bits &= bits - 1;
        comb[cpos++] = ((unsigned long long)T << 11) | (unsigned)(wd*32 + bit);
        --need;
      }
    }
  }
  __syncthreads();

  if (t < 64) {
    const unsigned long long mine = (t < NU) ? comb[t] : ~0ULL;
    int rank = 0;
#pragma unroll
    for (int step = 1; step < 64; ++step) {
      const unsigned long long other = __shfl(mine, (t + step) & 63);
      rank += (other < mine) ? 1 : 0;
    }
    if (t < NU) Mtop[bh*NU + rank] = (int)(mine & 0x7FFu);
  }
}

// ---------------------------------------------------------------- flash partials; nkt slabs (each block = 2048/nkt/64 slabs of 64 keys)
__global__ __launch_bounds__(256) void flash_partial(const float* __restrict__ qp,
                                                     const float* __restrict__ kp,
                                                     const float* __restrict__ vp,
                                                     const int* __restrict__ Mtop,
                                                     float* __restrict__ pm,
                                                     float* __restrict__ pl,
                                                     float* __restrict__ pacc,
                                                     int nkt) {
  __shared__ float qr[NU][65];
  __shared__ float kv[64][65];
  __shared__ float sl[NU][65];
  __shared__ float ms[NU], ls[NU], fs[NU];
  const int bid = blockIdx.x;
  const int bh = bid / nkt, kt = bid - bh*nkt;
  const int b = bh >> 3, h = bh & 7;
  const int spb = 32 / nkt;            // 64-key slabs per block
  const int t = threadIdx.x;
  const int g = t >> 6, j = t & 63;
  const int r4 = t >> 2, sub = t & 3;

  {
    const float* qbase = qp + (size_t)b*BHD + (size_t)h*QHS;
#pragma unroll
    for (int r = 0; r < 10; ++r) {
      const int q = g*10 + r;
      qr[q][j] = qbase[(size_t)Mtop[bh*NU + q]*64 + j];
    }
  }
  if (t < NU) { ms[t] = -INFINITY; ls[t] = 0.f; }
  float acc[10];
#pragma unroll
  for (int r = 0; r < 10; ++r) acc[r] = 0.f;

  const float* kbase = kp + (size_t)b*BHD + h*DH;
  const float* vbase = vp + (size_t)b*BHD + h*DH;
  const int srow = t >> 2, scb = (t & 3)*16;

  for (int st = 0; st < spb; ++st) {
    const int kb = (kt*spb + st)*64;
    __syncthreads();
    {
      const float* src = kbase + (size_t)(kb + srow)*512 + scb;
#pragma unroll
      for (int i = 0; i < 4; ++i) {
        float4 v = ld4(src + 4*i);
        kv[srow][scb + 4*i + 0] = v.x;
        kv[srow][scb + 4*i + 1] = v.y;
        kv[srow][scb + 4*i + 2] = v.z;
        kv[srow][scb + 4*i + 3] = v.w;
      }
    }
    __syncthreads();
    {
      float sv[10];
#pragma unroll
      for (int r = 0; r < 10; ++r) {
        const int q = g*10 + r;
        float s = 0.f;
#pragma unroll 8
        for (int jj = 0; jj < 64; ++jj) s += qr[q][jj]*kv[j][jj];
        sv[r] = s * 0.125f;
      }
#pragma unroll
      for (int r = 0; r < 10; ++r) sl[g*10 + r][j] = sv[r];
    }
    __syncthreads();
    float4 vst[4];
    {
      const float* src = vbase + (size_t)(kb + srow)*512 + scb;
#pragma unroll
      for (int i = 0; i < 4; ++i) vst[i] = ld4(src + 4*i);
    }
    if (r4 < NU) {
      float tm = -INFINITY;
#pragma unroll
      for (int c = 0; c < 16; ++c) tm = fmaxf(tm, sl[r4][sub*16 + c]);
      tm = fmaxf(tm, __shfl_xor(tm, 1));
      tm = fmaxf(tm, __shfl_xor(tm, 2));
      const float nm = fmaxf(ms[r4], tm);
      if (sub == 0) { fs[r4] = expf(ms[r4] - nm); ms[r4] = nm; }
    }
    __syncthreads();
    {
#pragma unroll
      for (int r = 0; r < 10; ++r) {
        const int q = g*10 + r;
        acc[r] *= fs[q];
        sl[q][j] = expf(sl[q][j] - ms[q]);
      }
#pragma unroll
      for (int i = 0; i < 4; ++i) {
        kv[srow][scb + 4*i + 0] = vst[i].x;
        kv[srow][scb + 4*i + 1] = vst[i].y;
        kv[srow][scb + 4*i + 2] = vst[i].z;
        kv[srow][scb + 4*i + 3] = vst[i].w;
      }
    }
    __syncthreads();
    if (r4 < NU) {
      float s = 0.f;
#pragma unroll
      for (int c = 0; c < 16; ++c) s += sl[r4][sub*16 + c];
      s += __shfl_xor(s, 1);
      s += __shfl_xor(s, 2);
      if (sub == 0) ls[r4] = ls[r4]*fs[r4] + s;
    }
    {
#pragma unroll 4
      for (int kk = 0; kk < 64; ++kk) {
        const float vv = kv[kk][j];
#pragma unroll
        for (int r = 0; r < 10; ++r) acc[r] += sl[g*10 + r][kk]*vv;
      }
    }
  }
  __syncthreads();
  const size_t base = (size_t)(bh*nkt + kt)*NU;
  if (t < NU) { pm[base + t] = ms[t]; pl[base + t] = ls[t]; }
#pragma unroll
  for (int r = 0; r < 10; ++r)
    pacc[(base + g*10 + r)*64 + j] = acc[r];
}

// ---------------------------------------------------------------- combine nkt partials, write outc (B,40,512)
__global__ __launch_bounds__(256) void flash_combine(const float* __restrict__ pm,
                                                     const float* __restrict__ pl,
                                                     const float* __restrict__ pacc,
                                                     float* __restrict__ outc,
                                                     int nkt) {
  const int t = threadIdx.x;
  const int qg = t >> 6, j = t & 63;
  const int bh = blockIdx.x / 10;
  const int q  = (blockIdx.x % 10)*4 + qg;
  const int b = bh >> 3, h = bh & 7;
  float m = -INFINITY;
  for (int kt = 0; kt < nkt; ++kt) m = fmaxf(m, pm[(size_t)(bh*nkt + kt)*NU + q]);
  float Lsum = 0.f, num = 0.f;
  for (int kt = 0; kt < nkt; ++kt) {
    const size_t base = (size_t)(bh*nkt + kt)*NU;
    const float w = expf(pm[base + q] - m);
    Lsum += w * pl[base + q];
    num  += w * pacc[(base + q)*64 + j];
  }
  outc[(size_t)(b*NU + q)*512 + h*64 + j] = num / Lsum;
}

// ---------------------------------------------------------------- Wo GEMM, split-k x4
__global__ __launch_bounds__(256) void wo_gemm(const float* __restrict__ outc,
                                               const float* __restrict__ Wo,
                                               float* __restrict__ pwo) {
  __shared__ __align__(16) float a_t[80][68];
  __shared__ __align__(16) float w_t[64][68];
  const int t = threadIdx.x;
  const int ty = t >> 4, tx = t & 15;
  const int nt = blockIdx.x, ks = blockIdx.y;
  float acc[5][4];
#pragma unroll
  for (int i = 0; i < 5; ++i)
#pragma unroll
    for (int j = 0; j < 4; ++j) acc[i][j] = 0.f;

  for (int c = 0; c < 2; ++c) {
    const int kb = ks*128 + c*64;
    __syncthreads();
#pragma unroll
    for (int i = 0; i < 20; ++i) {
      const int fi = t + 256*i;
      const int row = fi >> 6, col = fi & 63;
      a_t[row][col] = outc[(size_t)row*512 + kb + col];
    }
#pragma unroll
    for (int i = 0; i < 16; ++i) {
      const int fi = t + 256*i;
      const int row = fi >> 6, col = fi & 63;
      w_t[row][col] = Wo[(size_t)(nt*64 + row)*512 + kb + col];
    }
    __syncthreads();
    for (int gq = 0; gq < 16; ++gq) {
      float4 av[5], wv[4];
#pragma unroll
      for (int i = 0; i < 5; ++i) av[i] = *reinterpret_cast<const float4*>(&a_t[ty + 16*i][4*gq]);
#pragma unroll
      for (int j = 0; j < 4; ++j) wv[j] = *reinterpret_cast<const float4*>(&w_t[tx + 16*j][4*gq]);
#pragma unroll
      for (int i = 0; i < 5; ++i)
#pragma unroll
        for (int j = 0; j < 4; ++j) {
          acc[i][j] += av[i].x * wv[j].x;
          acc[i][j] += av[i].y * wv[j].y;
          acc[i][j] += av[i].z * wv[j].z;
          acc[i][j] += av[i].w * wv[j].w;
        }
    }
  }
#pragma unroll
  for (int i = 0; i < 5; ++i)
#pragma unroll
    for (int j = 0; j < 4; ++j)
      pwo[ks*40960 + (size_t)(ty + 16*i)*512 + nt*64 + tx + 16*j] = acc[i][j];
}

__global__ __launch_bounds__(256) void wo_combine(const float* __restrict__ pwo,
                                                  const float* __restrict__ bo,
                                                  float* __restrict__ out) {
  const int gi = blockIdx.x*256 + threadIdx.x;
  const float4* p = reinterpret_cast<const float4*>(pwo);
  const float4 a = p[gi], b4 = p[10240 + gi], c4 = p[20480 + gi], d4 = p[30720 + gi];
  const float4 bb = ld4(bo + 4*(gi & 127));
  float4 o;
  o.x = a.x + b4.x + c4.x + d4.x + bb.x;
  o.y = a.y + b4.y + c4.y + d4.y + bb.y;
  o.z = a.z + b4.z + c4.z + d4.z + bb.z;
  o.w = a.w + b4.w + c4.w + d4.w + bb.w;
  reinterpret_cast<float4*>(out)[gi] = o;
}

// ----------------------------------------------------------------
extern "C" void kernel_launch(void* const* d_in, const int* in_sizes, int n_in,
                              void* d_out, int out_size, void* d_ws, size_t ws_size,
                              hipStream_t stream) {
  const float* q  = (const float*)d_in[0];
  const float* k  = (const float*)d_in[1];
  const float* v  = (const float*)d_in[2];
  const float* Wq = (const float*)d_in[3];
  const float* bq = (const float*)d_in[4];
  const float* Wk = (const float*)d_in[5];
  const float* bk = (const float*)d_in[6];
  const float* Wv = (const float*)d_in[7];
  const float* bv = (const float*)d_in[8];
  const float* Wo = (const float*)d_in[9];
  const float* bo = (const float*)d_in[10];
  const int*  idx = (const int*)d_in[11];

  float* ws   = (float*)d_ws;
  float* qp   = ws;                        // 2,097,152
  float* kp   = ws + 2097152;              // 2,097,152
  float* vp   = ws + 4194304;              // 2,097,152
  int*   Mtop = (int*)(ws + 6292480);      // 640
  // nkt-dependent layout (all regions live after proj; wsp overlap is time-disjoint)
  const bool nkt32 = (ws_size >= (size_t)7685760 * 4);   // needs 30.75 MB
  const int  nkt   = nkt32 ? 32 : 16;
  float* pm   = ws + 6293120;              // nkt*16*40
  float* pl   = nkt32 ? (ws + 6313600) : (ws + 6303360);
  float* pacc = nkt32 ? (ws + 6334080) : (ws + 6313600); // nkt*16*40*64
  float* outc = nkt32 ? (ws + 7644800) : (ws + 6968960); // 40,960
  // time-disjoint aliases:
  float* Mp    = pm;                       // 131,072 (4 ks slices); dead before flash_partial
  float* pwo   = pm;                       // 163,840; written after flash_combine reads pm/pl/pacc
  unsigned short* wsp = (unsigned short*)(ws + 6291456); // live only during wsplit+proj
  int*   ulist = (int*)(ws + 6600000);     // 2177 ints, inside pacc region (dead until flash_partial)
  int*   ucnt  = ulist + 2176;
  float* kpart = ws + 6620000;             // 8,192; inside pacc region (read before flash_partial)

  const dim3 blk(256);
  const bool bigws = (ws_size >= (size_t)7471104 * 4);   // 3-mat W-split needs 29.9 MB
  if (bigws) {
    wsplit<<<dim3(32, 3), blk, 0, stream>>>(Wq, Wk, Wv, wsp, -1);
    proj_s<<<dim3(64, 4, 3), blk, 0, stream>>>(q, k, v, wsp, bq, bk, bv, qp, kp, vp, -1);
  } else {
    for (int m = 0; m < 3; ++m) {        // sequential per-mat fallback (identical numerics)
      wsplit<<<dim3(32, 1), blk, 0, stream>>>(Wq, Wk, Wv, wsp, m);
      proj_s<<<dim3(64, 4, 1), blk, 0, stream>>>(q, k, v, wsp, bq, bk, bv, qp, kp, vp, m);
    }
  }
  ksum_part<<<dim3(16, 8), dim3(1024), 0, stream>>>(kp, idx, kpart);
  dedupe<<<dim3(1), blk, 0, stream>>>(idx, ulist, ucnt);
  m_kernel<<<dim3(512), blk, 0, stream>>>(qp, kp, ulist, ucnt, Mp);
  topk_kernel<<<dim3(16), blk, 0, stream>>>(qp, kpart, Mp, Mtop);
  flash_partial<<<dim3(16*nkt), blk, 0, stream>>>(qp, kp, vp, Mtop, pm, pl, pacc, nkt);
  flash_combine<<<dim3(160), blk, 0, stream>>>(pm, pl, pacc, outc, nkt);
  wo_gemm<<<dim3(8, 4), blk, 0, stream>>>(outc, Wo, pwo);
  wo_combine<<<dim3(40), blk, 0, stream>>>(pwo, bo, (float*)d_out);
}

// Round 16
// 181.344 us; speedup vs baseline: 1.0376x; 1.0376x over previous
//
#include <hip/hip_runtime.h>
#include <math.h>

#define B_ 2
#define L_ 2048
#define D_ 512
#define H_ 8
#define DH 64
#define NS 2048   // U_part (sampled keys)
#define NU 40     // u (selected queries)
#define BHD (L_*D_)        // per-batch stride of qp/kp/vp
#define QHS (L_*DH)        // per-head stride inside qh view
#define WSPM 786432        // ushorts per mat in the W-split buffer

typedef __attribute__((ext_vector_type(8))) short bf16x8;
typedef __attribute__((ext_vector_type(4))) float f32x4;

__device__ inline float4 ld4(const float* p) { return *reinterpret_cast<const float4*>(p); }

// truncation split: x = h + m + r, all bf16-representable (exact truncations).
// 6-product MFMA (hh,hm,mh,mm,hl,lh) == fp32-class dot.
__device__ inline unsigned short hi16(float x) { return (unsigned short)(__float_as_uint(x) >> 16); }
__device__ inline float trunchf(float x) { return __uint_as_float(__float_as_uint(x) & 0xFFFF0000u); }
__device__ inline void tsplit(float x, unsigned short& hs, unsigned short& ms, unsigned short& ls) {
  float h = trunchf(x); hs = hi16(x);
  float r = x - h;                 // exact
  float m = trunchf(r); ms = hi16(r);
  float r2 = r - m;                // exact
  ls = hi16(r2);
}

// ---------------------------------------------------------------- W pre-split into fragment-direct layout
// dst layout: [p(3)][nt(4)][g16(8)][kc(16)][lane(64)][8] ushorts per mat.
__global__ __launch_bounds__(256) void wsplit(const float* __restrict__ Wq,
                                              const float* __restrict__ Wk,
                                              const float* __restrict__ Wv,
                                              unsigned short* __restrict__ dst,
                                              int matArg) {
  const int mat = (matArg >= 0) ? matArg : (int)blockIdx.y;
  const float* W = (mat == 0) ? Wq : (mat == 1) ? Wk : Wv;
  unsigned short* d = dst + ((matArg >= 0) ? 0 : (size_t)mat * WSPM);
  const int t = threadIdx.x;
  const int nt = blockIdx.x >> 3, g16 = blockIdx.x & 7;
  const int kc = t >> 4, lr = t & 15;
  const int n = nt*128 + g16*16 + lr;
  const float* src = W + (size_t)n*512 + kc*32;
  float xs[32];
#pragma unroll
  for (int i = 0; i < 8; ++i) {
    float4 v4 = ld4(src + 4*i);
    xs[4*i] = v4.x; xs[4*i+1] = v4.y; xs[4*i+2] = v4.z; xs[4*i+3] = v4.w;
  }
  unsigned short Hs[32], Ms[32], Ls[32];
#pragma unroll
  for (int e = 0; e < 32; ++e) tsplit(xs[e], Hs[e], Ms[e], Ls[e]);
#pragma unroll
  for (int p = 0; p < 3; ++p) {
    const unsigned short* sp = (p == 0) ? Hs : (p == 1) ? Ms : Ls;
    unsigned short* base = d + ((size_t)((p*4 + nt)*8 + g16)*16 + kc)*512;
#pragma unroll
    for (int lg = 0; lg < 4; ++lg) {
      union { bf16x8 v; unsigned short u[8]; } P;
#pragma unroll
      for (int e = 0; e < 8; ++e) P.u[e] = sp[lg*8 + e];
      *reinterpret_cast<bf16x8*>(base + (lr + 16*lg)*8) = P.v;
    }
  }
}

// ---------------------------------------------------------------- projection GEMM, small-tile split-bf16 MFMA
// Block 64x128 (4 waves, each 64x32: mi=4, ni=2). Grid 768 = 3 blocks/CU.
__global__ __launch_bounds__(256, 3) void proj_s(
    const float* __restrict__ qa, const float* __restrict__ ka, const float* __restrict__ va,
    const unsigned short* __restrict__ wsp,
    const float* __restrict__ bq, const float* __restrict__ bk, const float* __restrict__ bv,
    float* __restrict__ qp, float* __restrict__ kp, float* __restrict__ vp,
    int matArg)
{
  __shared__ __align__(16) unsigned short a3[2][3][64][36];
  const int t = threadIdx.x;
  const int mat = (matArg >= 0) ? matArg : (int)blockIdx.z;
  const float* A    = (mat == 0) ? qa : (mat == 1) ? ka : va;
  const float* bias = (mat == 0) ? bq : (mat == 1) ? bk : bv;
  float* C          = (mat == 0) ? qp : (mat == 1) ? kp : vp;
  const unsigned short* wspm = wsp + ((matArg >= 0) ? 0 : (size_t)mat * WSPM);
  const int m0 = blockIdx.x * 64, NT = blockIdx.y;
  const int wn = t >> 6, l = t & 63;
  const int lr = l & 15, lg = l >> 4;
  const int srow = t >> 2, scf = (t & 3) * 8;
  const float* aRow = A + (size_t)(m0 + srow) * 512 + scf;

  f32x4 acc[4][2];
#pragma unroll
  for (int i = 0; i < 4; ++i)
#pragma unroll
    for (int j = 0; j < 2; ++j) acc[i][j] = (f32x4){0.f, 0.f, 0.f, 0.f};

#define LOADW(dst, kcv)                                                        \
  _Pragma("unroll")                                                            \
  for (int p = 0; p < 3; ++p)                                                  \
    _Pragma("unroll")                                                          \
    for (int ni = 0; ni < 2; ++ni)                                             \
      dst[p][ni] = *reinterpret_cast<const bf16x8*>(                           \
          wspm + ((size_t)((p*4 + NT)*8 + wn*2 + ni)*16 + (kcv))*512 + l*8);

#define SPLITSTORE(r0, r1, buf)                                                \
  {                                                                            \
    float xs[8] = {r0.x, r0.y, r0.z, r0.w, r1.x, r1.y, r1.z, r1.w};            \
    union { bf16x8 v; unsigned short u[8]; } H, M, L;                          \
    _Pragma("unroll")                                                          \
    for (int e = 0; e < 8; ++e) tsplit(xs[e], H.u[e], M.u[e], L.u[e]);         \
    *reinterpret_cast<bf16x8*>(&a3[buf][0][srow][scf]) = H.v;                  \
    *reinterpret_cast<bf16x8*>(&a3[buf][1][srow][scf]) = M.v;                  \
    *reinterpret_cast<bf16x8*>(&a3[buf][2][srow][scf]) = L.v;                  \
  }

#define MFMA6(buf, bw)                                                         \
  __builtin_amdgcn_s_setprio(1);                                               \
  _Pragma("unroll")                                                            \
  for (int mi = 0; mi < 4; ++mi) {                                             \
    bf16x8 a0 = *reinterpret_cast<const bf16x8*>(&a3[buf][0][mi*16 + lr][lg*8]); \
    bf16x8 a1 = *reinterpret_cast<const bf16x8*>(&a3[buf][1][mi*16 + lr][lg*8]); \
    bf16x8 a2 = *reinterpret_cast<const bf16x8*>(&a3[buf][2][mi*16 + lr][lg*8]); \
    _Pragma("unroll")                                                          \
    for (int ni = 0; ni < 2; ++ni) {                                           \
      acc[mi][ni] = __builtin_amdgcn_mfma_f32_16x16x32_bf16(a0, bw[0][ni], acc[mi][ni], 0, 0, 0); \
      acc[mi][ni] = __builtin_amdgcn_mfma_f32_16x16x32_bf16(a0, bw[1][ni], acc[mi][ni], 0, 0, 0); \
      acc[mi][ni] = __builtin_amdgcn_mfma_f32_16x16x32_bf16(a1, bw[0][ni], acc[mi][ni], 0, 0, 0); \
      acc[mi][ni] = __builtin_amdgcn_mfma_f32_16x16x32_bf16(a1, bw[1][ni], acc[mi][ni], 0, 0, 0); \
      acc[mi][ni] = __builtin_amdgcn_mfma_f32_16x16x32_bf16(a0, bw[2][ni], acc[mi][ni], 0, 0, 0); \
      acc[mi][ni] = __builtin_amdgcn_mfma_f32_16x16x32_bf16(a2, bw[0][ni], acc[mi][ni], 0, 0, 0); \
    }                                                                          \
  }                                                                            \
  __builtin_amdgcn_s_setprio(0);

  float4 arA0 = ld4(aRow), arA1 = ld4(aRow + 4);
  bf16x8 bwA[3][2], bwB[3][2];
  LOADW(bwA, 0);
  float4 arB0, arB1;

  for (int kc = 0; kc < 16; kc += 2) {
    SPLITSTORE(arA0, arA1, 0);
    __syncthreads();
    if (kc < 15) {
      const float* src = aRow + (kc+1)*32;
      arB0 = ld4(src); arB1 = ld4(src + 4);
      LOADW(bwB, kc+1);
    }
    MFMA6(0, bwA);
    SPLITSTORE(arB0, arB1, 1);
    __syncthreads();
    if (kc + 2 < 16) {
      const float* src = aRow + (kc+2)*32;
      arA0 = ld4(src); arA1 = ld4(src + 4);
      LOADW(bwA, kc+2);
    }
    MFMA6(1, bwB);
  }
#undef LOADW
#undef SPLITSTORE
#undef MFMA6

#pragma unroll
  for (int mi = 0; mi < 4; ++mi)
#pragma unroll
    for (int ni = 0; ni < 2; ++ni) {
      const int gn = NT*128 + wn*32 + ni*16 + lr;
      const float bv_ = bias[gn];
#pragma unroll
      for (int r = 0; r < 4; ++r) {
        const int gm = m0 + mi*16 + lg*4 + r;
        C[(size_t)gm * 512 + gn] = acc[mi][ni][r] + bv_;
      }
    }
}

// ---------------------------------------------------------------- Ksum[bh][j] = sum_s kp[b, idx[s], h*64+j]
__global__ __launch_bounds__(1024) void ksum_kernel(const float* __restrict__ kp,
                                                    const int* __restrict__ idx,
                                                    float* __restrict__ ksum) {
  __shared__ float part[16][64];
  const int bh = blockIdx.x;
  const int b = bh >> 3, h = bh & 7;
  const int t = threadIdx.x;
  const int sg = t >> 6, j = t & 63;
  const float* kbase = kp + (size_t)b*BHD + h*DH;
  float a = 0.f;
  for (int s = sg*128; s < sg*128 + 128; ++s)
    a += kbase[(size_t)idx[s]*512 + j];
  part[sg][j] = a;
  __syncthreads();
  if (t < 64) {
    float s = 0.f;
#pragma unroll
    for (int i = 0; i < 16; ++i) s += part[i][t];
    ksum[bh*64 + t] = s;
  }
}

// ---------------------------------------------------------------- dedupe sampled indices (max over multiset == max over unique set)
// ulist: unique indices (ascending), padded to multiple of 128 with ulist[0]; ucnt[0] = 128-key tile count
__global__ __launch_bounds__(256) void dedupe(const int* __restrict__ idx,
                                              int* __restrict__ ulist,
                                              int* __restrict__ ucnt) {
  __shared__ unsigned bm[64];
  __shared__ int base[64];
  __shared__ int total;
  const int t = threadIdx.x;
  if (t < 64) bm[t] = 0;
  __syncthreads();
#pragma unroll
  for (int c = 0; c < 8; ++c) {
    const int v = idx[c*256 + t];
    atomicOr(&bm[v >> 5], 1u << (v & 31));
  }
  __syncthreads();
  if (t < 64) {
    const int cnt = __popc(bm[t]);
    int inc = cnt;
#pragma unroll
    for (int off = 1; off < 64; off <<= 1) {
      const int nb = __shfl_up(inc, off);
      if (t >= off) inc += nb;
    }
    base[t] = inc - cnt;
    if (t == 63) total = inc;
  }
  __syncthreads();
  if (t < 64) {
    unsigned w = bm[t];
    int pos = base[t];
    while (w) {
      const int b = __ffs(w) - 1;
      w &= w - 1;
      ulist[pos++] = t*32 + b;
    }
  }
  __syncthreads();
  const int U = total;
  const int nt = (U + 127) >> 7;
  const int padded = nt << 7;
  const int first = ulist[0];
  for (int p = U + t; p < padded; p += 256) ulist[p] = first;
  if (t == 0) ucnt[0] = nt;
}

// ---------------------------------------------------------------- Mp[ks][bh][q] = max over this ks-slice of unique keys
// 128-key LDS tiles, grid 512 (bh=bid>>5, qt=(bid>>2)&7, ks=bid&3), 2 blocks/CU.
// Tiles of ulist round-robin ks, ks+4, ... (~2-3 tiles/block at U~1300).
__global__ __launch_bounds__(256, 2) void m_kernel(const float* __restrict__ qp,
                                                   const float* __restrict__ kp,
                                                   const int* __restrict__ ulist,
                                                   const int* __restrict__ ucnt,
                                                   float* __restrict__ Mp) {
  __shared__ __align__(16) unsigned short k3[3][128][72];
  const int t = threadIdx.x;
  const int bid = blockIdx.x;
  const int bh = bid >> 5, qt = (bid >> 2) & 7, ks = bid & 3;
  const int b = bh >> 3, h = bh & 7;
  const int w = t >> 6, l = t & 63;
  const int lr = l & 15;
  const int lg = l >> 4;

  bf16x8 qf[4][2][3];
  {
    const float* qbase = qp + (size_t)b*BHD + (size_t)h*QHS + (size_t)(qt*256 + w*64 + lr) * 64 + lg*8;
#pragma unroll
    for (int mi = 0; mi < 4; ++mi)
#pragma unroll
      for (int c = 0; c < 2; ++c) {
        const float* src = qbase + mi*16*64 + c*32;
        float4 x0 = ld4(src), x1 = ld4(src + 4);
        float xs[8] = {x0.x, x0.y, x0.z, x0.w, x1.x, x1.y, x1.z, x1.w};
        union { bf16x8 v; unsigned short u[8]; } H, M, L;
#pragma unroll
        for (int e = 0; e < 8; ++e) tsplit(xs[e], H.u[e], M.u[e], L.u[e]);
        qf[mi][c][0] = H.v; qf[mi][c][1] = M.v; qf[mi][c][2] = L.v;
      }
  }

  const float* kbase = kp + (size_t)b*BHD + h*DH;
  const int ntiles = ucnt[0];
  const int srow = t >> 1, sh = (t & 1) * 32;

  float4 vst[8];
  if (ks < ntiles) {
    const int kr = ulist[ks*128 + srow];
    const float* src = kbase + (size_t)kr * 512 + sh;
#pragma unroll
    for (int i = 0; i < 8; ++i) vst[i] = ld4(src + 4*i);
  }

  float mx[4][4];
#pragma unroll
  for (int mi = 0; mi < 4; ++mi)
#pragma unroll
    for (int r = 0; r < 4; ++r) mx[mi][r] = -INFINITY;

  for (int ti = ks; ti < ntiles; ti += 4) {
    __syncthreads();
    {
#pragma unroll
      for (int e2 = 0; e2 < 4; ++e2) {
        union { bf16x8 v; unsigned short u[8]; } H, M, L;
        float xs[8] = {vst[2*e2].x, vst[2*e2].y, vst[2*e2].z, vst[2*e2].w,
                       vst[2*e2+1].x, vst[2*e2+1].y, vst[2*e2+1].z, vst[2*e2+1].w};
#pragma unroll
        for (int e = 0; e < 8; ++e) tsplit(xs[e], H.u[e], M.u[e], L.u[e]);
        *reinterpret_cast<bf16x8*>(&k3[0][srow][sh + 8*e2]) = H.v;
        *reinterpret_cast<bf16x8*>(&k3[1][srow][sh + 8*e2]) = M.v;
        *reinterpret_cast<bf16x8*>(&k3[2][srow][sh + 8*e2]) = L.v;
      }
    }
    if (ti + 4 < ntiles) {
      const int kr = ulist[(ti+4)*128 + srow];
      const float* src = kbase + (size_t)kr * 512 + sh;
#pragma unroll
      for (int i = 0; i < 8; ++i) vst[i] = ld4(src + 4*i);
    }
    __syncthreads();

    for (int n2 = 0; n2 < 4; ++n2) {
      bf16x8 bf[2][3][2];
#pragma unroll
      for (int ns = 0; ns < 2; ++ns)
#pragma unroll
        for (int p = 0; p < 3; ++p)
#pragma unroll
          for (int c = 0; c < 2; ++c)
            bf[ns][p][c] = *reinterpret_cast<const bf16x8*>(&k3[p][n2*32 + ns*16 + lr][c*32 + lg*8]);
      __builtin_amdgcn_s_setprio(1);
#pragma unroll
      for (int mi = 0; mi < 4; ++mi)
#pragma unroll
        for (int ns = 0; ns < 2; ++ns) {
          f32x4 acc = {0.f, 0.f, 0.f, 0.f};
#pragma unroll
          for (int c = 0; c < 2; ++c) acc = __builtin_amdgcn_mfma_f32_16x16x32_bf16(qf[mi][c][0], bf[ns][0][c], acc, 0, 0, 0); // hh
#pragma unroll
          for (int c = 0; c < 2; ++c) acc = __builtin_amdgcn_mfma_f32_16x16x32_bf16(qf[mi][c][0], bf[ns][1][c], acc, 0, 0, 0); // hm
#pragma unroll
          for (int c = 0; c < 2; ++c) acc = __builtin_amdgcn_mfma_f32_16x16x32_bf16(qf[mi][c][1], bf[ns][0][c], acc, 0, 0, 0); // mh
#pragma unroll
          for (int c = 0; c < 2; ++c) acc = __builtin_amdgcn_mfma_f32_16x16x32_bf16(qf[mi][c][1], bf[ns][1][c], acc, 0, 0, 0); // mm
#pragma unroll
          for (int c = 0; c < 2; ++c) acc = __builtin_amdgcn_mfma_f32_16x16x32_bf16(qf[mi][c][0], bf[ns][2][c], acc, 0, 0, 0); // hl
#pragma unroll
          for (int c = 0; c < 2; ++c) acc = __builtin_amdgcn_mfma_f32_16x16x32_bf16(qf[mi][c][2], bf[ns][0][c], acc, 0, 0, 0); // lh
#pragma unroll
          for (int r = 0; r < 4; ++r) mx[mi][r] = fmaxf(mx[mi][r], acc[r]);
        }
      __builtin_amdgcn_s_setprio(0);
    }
  }

#pragma unroll
  for (int mi = 0; mi < 4; ++mi)
#pragma unroll
    for (int r = 0; r < 4; ++r) {
      float v = mx[mi][r];
      v = fmaxf(v, __shfl_xor(v, 1));
      v = fmaxf(v, __shfl_xor(v, 2));
      v = fmaxf(v, __shfl_xor(v, 4));
      v = fmaxf(v, __shfl_xor(v, 8));
      if (lr == 0)
        Mp[ks*32768 + bh*2048 + qt*256 + w*64 + mi*16 + lg*4 + r] = v;
    }
}

// ---------------------------------------------------------------- fused M-finalize + top-40 via radix-select
__global__ __launch_bounds__(256) void topk_kernel(const float* __restrict__ qp,
                                                   const float* __restrict__ ksum,
                                                   const float* __restrict__ Mp,
                                                   int* __restrict__ Mtop) {
  __shared__ float ks_s[64];
  __shared__ unsigned hist[256];
  __shared__ int wsum[4];
  __shared__ unsigned bitmap[64];
  __shared__ unsigned long long comb[NU];
  __shared__ int s_sel, s_rem, s_cnt;
  const int bh = blockIdx.x;
  const int b = bh >> 3, h = bh & 7;
  const int t = threadIdx.x;
  if (t < 64) ks_s[t] = ksum[bh*64 + t];
  __syncthreads();

  unsigned mykey[8];
#pragma unroll
  for (int c = 0; c < 8; ++c) {
    const int qi = c * 256 + t;
    const float* qrow = qp + (size_t)b*BHD + (size_t)h*QHS + (size_t)qi * 64;
    float dot = 0.f;
#pragma unroll
    for (int cc = 0; cc < 16; ++cc) {
      float4 q4 = ld4(qrow + 4 * cc);
      dot += q4.x * ks_s[4*cc + 0];
      dot += q4.y * ks_s[4*cc + 1];
      dot += q4.z * ks_s[4*cc + 2];
      dot += q4.w * ks_s[4*cc + 3];
    }
    const float mx2 = fmaxf(fmaxf(Mp[bh*2048 + qi], Mp[32768 + bh*2048 + qi]),
                            fmaxf(Mp[65536 + bh*2048 + qi], Mp[98304 + bh*2048 + qi]));
    const float m = mx2 - dot * (1.0f/2048.0f);
    const unsigned u = __float_as_uint(m);
    mykey[c] = (u >> 31) ? ~u : (u | 0x80000000u);
  }

  unsigned prefMask = 0u, prefVal = 0u;
  int rem = NU;
  for (int shift = 24; shift >= 0; shift -= 8) {
    hist[t] = 0;
    __syncthreads();
#pragma unroll
    for (int c = 0; c < 8; ++c) {
      const unsigned key = mykey[c];
      if ((key & prefMask) == prefVal)
        atomicAdd(&hist[(key >> shift) & 255], 1u);
    }
    __syncthreads();
    const int binc = (int)hist[t];
    int inc = binc;
#pragma unroll
    for (int off = 1; off < 64; off <<= 1) {
      const int nb = __shfl_up(inc, off);
      if ((t & 63) >= off) inc += nb;
    }
    if ((t & 63) == 63) wsum[t >> 6] = inc;
    __syncthreads();
    int wadd = 0;
    for (int w2 = 0; w2 < (t >> 6); ++w2) wadd += wsum[w2];
    const int incl = inc + wadd;
    const int excl = incl - binc;
    if (excl < rem && rem <= incl) { s_sel = t; s_rem = rem - excl; }
    __syncthreads();
    prefVal |= ((unsigned)s_sel) << shift;
    prefMask |= 0xFFu << shift;
    rem = s_rem;
    __syncthreads();
  }
  const unsigned T = prefVal;

  if (t < 64) bitmap[t] = 0;
  if (t == 0) s_cnt = 0;
  __syncthreads();
#pragma unroll
  for (int c = 0; c < 8; ++c) {
    const unsigned key = mykey[c];
    const int qi = c * 256 + t;
    if (key < T) {
      const int pos = atomicAdd(&s_cnt, 1);
      comb[pos] = ((unsigned long long)key << 11) | (unsigned)qi;
    } else if (key == T) {
      atomicOr(&bitmap[qi >> 5], 1u << (qi & 31));
    }
  }
  __syncthreads();
  if (t == 0) {
    int need = rem, cpos = s_cnt;
    for (int wd = 0; wd < 64 && need > 0; ++wd) {
      unsigned bits = bitmap[wd];
      while (bits && need > 0) {
        const int bit = __ffs(bits) - 1;
        bits &= bits - 1;
        comb[cpos++] = ((unsigned long long)T << 11) | (unsigned)(wd*32 + bit);
        --need;
      }
    }
  }
  __syncthreads();

  if (t < 64) {
    const unsigned long long mine = (t < NU) ? comb[t] : ~0ULL;
    int rank = 0;
#pragma unroll
    for (int step = 1; step < 64; ++step) {
      const unsigned long long other = __shfl(mine, (t + step) & 63);
      rank += (other < mine) ? 1 : 0;
    }
    if (t < NU) Mtop[bh*NU + rank] = (int)(mine & 0x7FFu);
  }
}

// ---------------------------------------------------------------- flash partials over 128-key slabs
__global__ __launch_bounds__(256) void flash_partial(const float* __restrict__ qp,
                                                     const float* __restrict__ kp,
                                                     const float* __restrict__ vp,
                                                     const int* __restrict__ Mtop,
                                                     float* __restrict__ pm,
                                                     float* __restrict__ pl,
                                                     float* __restrict__ pacc) {
  __shared__ float qr[NU][65];
  __shared__ float kv[64][65];
  __shared__ float sl[NU][65];
  __shared__ float ms[NU], ls[NU], fs[NU];
  const int bid = blockIdx.x;
  const int bh = bid >> 4, kt = bid & 15;
  const int b = bh >> 3, h = bh & 7;
  const int t = threadIdx.x;
  const int g = t >> 6, j = t & 63;
  const int r4 = t >> 2, sub = t & 3;

  {
    const float* qbase = qp + (size_t)b*BHD + (size_t)h*QHS;
#pragma unroll
    for (int r = 0; r < 10; ++r) {
      const int q = g*10 + r;
      qr[q][j] = qbase[(size_t)Mtop[bh*NU + q]*64 + j];
    }
  }
  if (t < NU) { ms[t] = -INFINITY; ls[t] = 0.f; }
  float acc[10];
#pragma unroll
  for (int r = 0; r < 10; ++r) acc[r] = 0.f;

  const float* kbase = kp + (size_t)b*BHD + h*DH;
  const float* vbase = vp + (size_t)b*BHD + h*DH;
  const int srow = t >> 2, scb = (t & 3)*16;

  for (int st = 0; st < 2; ++st) {
    const int kb = kt*128 + st*64;
    __syncthreads();
    {
      const float* src = kbase + (size_t)(kb + srow)*512 + scb;
#pragma unroll
      for (int i = 0; i < 4; ++i) {
        float4 v = ld4(src + 4*i);
        kv[srow][scb + 4*i + 0] = v.x;
        kv[srow][scb + 4*i + 1] = v.y;
        kv[srow][scb + 4*i + 2] = v.z;
        kv[srow][scb + 4*i + 3] = v.w;
      }
    }
    __syncthreads();
    {
      float sv[10];
#pragma unroll
      for (int r = 0; r < 10; ++r) {
        const int q = g*10 + r;
        float s = 0.f;
#pragma unroll 8
        for (int jj = 0; jj < 64; ++jj) s += qr[q][jj]*kv[j][jj];
        sv[r] = s * 0.125f;
      }
#pragma unroll
      for (int r = 0; r < 10; ++r) sl[g*10 + r][j] = sv[r];
    }
    __syncthreads();
    float4 vst[4];
    {
      const float* src = vbase + (size_t)(kb + srow)*512 + scb;
#pragma unroll
      for (int i = 0; i < 4; ++i) vst[i] = ld4(src + 4*i);
    }
    if (r4 < NU) {
      float tm = -INFINITY;
#pragma unroll
      for (int c = 0; c < 16; ++c) tm = fmaxf(tm, sl[r4][sub*16 + c]);
      tm = fmaxf(tm, __shfl_xor(tm, 1));
      tm = fmaxf(tm, __shfl_xor(tm, 2));
      const float nm = fmaxf(ms[r4], tm);
      if (sub == 0) { fs[r4] = expf(ms[r4] - nm); ms[r4] = nm; }
    }
    __syncthreads();
    {
#pragma unroll
      for (int r = 0; r < 10; ++r) {
        const int q = g*10 + r;
        acc[r] *= fs[q];
        sl[q][j] = expf(sl[q][j] - ms[q]);
      }
#pragma unroll
      for (int i = 0; i < 4; ++i) {
        kv[srow][scb + 4*i + 0] = vst[i].x;
        kv[srow][scb + 4*i + 1] = vst[i].y;
        kv[srow][scb + 4*i + 2] = vst[i].z;
        kv[srow][scb + 4*i + 3] = vst[i].w;
      }
    }
    __syncthreads();
    if (r4 < NU) {
      float s = 0.f;
#pragma unroll
      for (int c = 0; c < 16; ++c) s += sl[r4][sub*16 + c];
      s += __shfl_xor(s, 1);
      s += __shfl_xor(s, 2);
      if (sub == 0) ls[r4] = ls[r4]*fs[r4] + s;
    }
    {
#pragma unroll 4
      for (int kk = 0; kk < 64; ++kk) {
        const float vv = kv[kk][j];
#pragma unroll
        for (int r = 0; r < 10; ++r) acc[r] += sl[g*10 + r][kk]*vv;
      }
    }
  }
  __syncthreads();
  const size_t base = (size_t)(bh*16 + kt)*NU;
  if (t < NU) { pm[base + t] = ms[t]; pl[base + t] = ls[t]; }
#pragma unroll
  for (int r = 0; r < 10; ++r)
    pacc[(base + g*10 + r)*64 + j] = acc[r];
}

// ---------------------------------------------------------------- combine 16 partials, write outc (B,40,512)
__global__ __launch_bounds__(256) void flash_combine(const float* __restrict__ pm,
                                                     const float* __restrict__ pl,
                                                     const float* __restrict__ pacc,
                                                     float* __restrict__ outc) {
  const int t = threadIdx.x;
  const int qg = t >> 6, j = t & 63;
  const int bh = blockIdx.x / 10;
  const int q  = (blockIdx.x % 10)*4 + qg;
  const int b = bh >> 3, h = bh & 7;
  float m = -INFINITY;
#pragma unroll
  for (int kt = 0; kt < 16; ++kt) m = fmaxf(m, pm[(size_t)(bh*16 + kt)*NU + q]);
  float Lsum = 0.f, num = 0.f;
#pragma unroll
  for (int kt = 0; kt < 16; ++kt) {
    const size_t base = (size_t)(bh*16 + kt)*NU;
    const float w = expf(pm[base + q] - m);
    Lsum += w * pl[base + q];
    num  += w * pacc[(base + q)*64 + j];
  }
  outc[(size_t)(b*NU + q)*512 + h*64 + j] = num / Lsum;
}

// ---------------------------------------------------------------- Wo GEMM, split-k x4
__global__ __launch_bounds__(256) void wo_gemm(const float* __restrict__ outc,
                                               const float* __restrict__ Wo,
                                               float* __restrict__ pwo) {
  __shared__ __align__(16) float a_t[80][68];
  __shared__ __align__(16) float w_t[64][68];
  const int t = threadIdx.x;
  const int ty = t >> 4, tx = t & 15;
  const int nt = blockIdx.x, ks = blockIdx.y;
  float acc[5][4];
#pragma unroll
  for (int i = 0; i < 5; ++i)
#pragma unroll
    for (int j = 0; j < 4; ++j) acc[i][j] = 0.f;

  for (int c = 0; c < 2; ++c) {
    const int kb = ks*128 + c*64;
    __syncthreads();
#pragma unroll
    for (int i = 0; i < 20; ++i) {
      const int fi = t + 256*i;
      const int row = fi >> 6, col = fi & 63;
      a_t[row][col] = outc[(size_t)row*512 + kb + col];
    }
#pragma unroll
    for (int i = 0; i < 16; ++i) {
      const int fi = t + 256*i;
      const int row = fi >> 6, col = fi & 63;
      w_t[row][col] = Wo[(size_t)(nt*64 + row)*512 + kb + col];
    }
    __syncthreads();
    for (int gq = 0; gq < 16; ++gq) {
      float4 av[5], wv[4];
#pragma unroll
      for (int i = 0; i < 5; ++i) av[i] = *reinterpret_cast<const float4*>(&a_t[ty + 16*i][4*gq]);
#pragma unroll
      for (int j = 0; j < 4; ++j) wv[j] = *reinterpret_cast<const float4*>(&w_t[tx + 16*j][4*gq]);
#pragma unroll
      for (int i = 0; i < 5; ++i)
#pragma unroll
        for (int j = 0; j < 4; ++j) {
          acc[i][j] += av[i].x * wv[j].x;
          acc[i][j] += av[i].y * wv[j].y;
          acc[i][j] += av[i].z * wv[j].z;
          acc[i][j] += av[i].w * wv[j].w;
        }
    }
  }
#pragma unroll
  for (int i = 0; i < 5; ++i)
#pragma unroll
    for (int j = 0; j < 4; ++j)
      pwo[ks*40960 + (size_t)(ty + 16*i)*512 + nt*64 + tx + 16*j] = acc[i][j];
}

__global__ __launch_bounds__(256) void wo_combine(const float* __restrict__ pwo,
                                                  const float* __restrict__ bo,
                                                  float* __restrict__ out) {
  const int gi = blockIdx.x*256 + threadIdx.x;
  const float4* p = reinterpret_cast<const float4*>(pwo);
  const float4 a = p[gi], b4 = p[10240 + gi], c4 = p[20480 + gi], d4 = p[30720 + gi];
  const float4 bb = ld4(bo + 4*(gi & 127));
  float4 o;
  o.x = a.x + b4.x + c4.x + d4.x + bb.x;
  o.y = a.y + b4.y + c4.y + d4.y + bb.y;
  o.z = a.z + b4.z + c4.z + d4.z + bb.z;
  o.w = a.w + b4.w + c4.w + d4.w + bb.w;
  reinterpret_cast<float4*>(out)[gi] = o;
}

// ----------------------------------------------------------------
extern "C" void kernel_launch(void* const* d_in, const int* in_sizes, int n_in,
                              void* d_out, int out_size, void* d_ws, size_t ws_size,
                              hipStream_t stream) {
  const float* q  = (const float*)d_in[0];
  const float* k  = (const float*)d_in[1];
  const float* v  = (const float*)d_in[2];
  const float* Wq = (const float*)d_in[3];
  const float* bq = (const float*)d_in[4];
  const float* Wk = (const float*)d_in[5];
  const float* bk = (const float*)d_in[6];
  const float* Wv = (const float*)d_in[7];
  const float* bv = (const float*)d_in[8];
  const float* Wo = (const float*)d_in[9];
  const float* bo = (const float*)d_in[10];
  const int*  idx = (const int*)d_in[11];

  float* ws   = (float*)d_ws;
  float* qp   = ws;                        // 2,097,152
  float* kp   = ws + 2097152;              // 2,097,152
  float* vp   = ws + 4194304;              // 2,097,152
  float* ksum = ws + 6291456;              // 1,024
  int*   Mtop = (int*)(ws + 6292480);      // 640
  float* pm   = ws + 6293120;              // 10,240
  float* pl   = ws + 6303360;              // 10,240
  float* pacc = ws + 6313600;              // 655,360
  float* outc = ws + 6968960;              // 40,960  (end 7,009,920)
  // time-disjoint aliases:
  float* Mp   = pm;                        // 131,072 needed (4 ks-slices); dead before flash_partial
  float* pwo  = pm;                        // written after flash_combine reads pm/pl/pacc
  unsigned short* wsp = (unsigned short*)(ws + 6291456);  // live only during wsplit+proj
  int* ulist = (int*)(ws + 6600000);       // 2176 ints, inside pacc region (dead until flash_partial)
  int* ucnt  = ulist + 2176;

  const dim3 blk(256);
  const bool bigws = (ws_size >= (size_t)7471104 * 4);   // 3-mat W-split extends ws to 29.9 MB
  if (bigws) {
    wsplit<<<dim3(32, 3), blk, 0, stream>>>(Wq, Wk, Wv, wsp, -1);
    proj_s<<<dim3(64, 4, 3), blk, 0, stream>>>(q, k, v, wsp, bq, bk, bv, qp, kp, vp, -1);
  } else {
    for (int m = 0; m < 3; ++m) {        // sequential per-mat fallback (identical numerics)
      wsplit<<<dim3(32, 1), blk, 0, stream>>>(Wq, Wk, Wv, wsp, m);
      proj_s<<<dim3(64, 4, 1), blk, 0, stream>>>(q, k, v, wsp, bq, bk, bv, qp, kp, vp, m);
    }
  }
  ksum_kernel<<<dim3(16), dim3(1024), 0, stream>>>(kp, idx, ksum);
  dedupe<<<dim3(1), blk, 0, stream>>>(idx, ulist, ucnt);
  m_kernel<<<dim3(512), blk, 0, stream>>>(qp, kp, ulist, ucnt, Mp);
  topk_kernel<<<dim3(16), blk, 0, stream>>>(qp, ksum, Mp, Mtop);
  flash_partial<<<dim3(256), blk, 0, stream>>>(qp, kp, vp, Mtop, pm, pl, pacc);
  flash_combine<<<dim3(160), blk, 0, stream>>>(pm, pl, pacc, outc);
  wo_gemm<<<dim3(8, 4), blk, 0, stream>>>(outc, Wo, pwo);
  wo_combine<<<dim3(40), blk, 0, stream>>>(pwo, bo, (float*)d_out);
}